// Round 2
// baseline (634.314 us; speedup 1.0000x reference)
//
#include <hip/hip_runtime.h>
#include <hip/hip_bf16.h>
#include <stdint.h>

// Problem constants: B=4, T=2048, C=1024, E=8, H=2048, K=2
#define NB 4
#define NTT 2048
#define NC 1024
#define NE 8
#define NH 2048
#define NKK 2
#define NTOK (NB * NTT)            // 8192
#define CAP (2 * NTOK * NKK / NE)  // 4096

typedef __hip_bfloat16 bf16;
typedef __attribute__((ext_vector_type(8))) short short8;
typedef __attribute__((ext_vector_type(4))) short short4v;
typedef __attribute__((ext_vector_type(4))) float floatx4;

typedef const __attribute__((address_space(1))) void* gas_ptr;
typedef __attribute__((address_space(3))) void* las_ptr;

static __device__ __forceinline__ void async_copy16(const void* g, void* l) {
  // 16B/lane; LDS dest = wave-uniform base + lane*16 (m97/m104 semantics).
  // Our la[] addresses are exactly lane-contiguous in that order.
  __builtin_amdgcn_global_load_lds((gas_ptr)g, (las_ptr)l, 16, 0, 0);
}

static __device__ __forceinline__ unsigned short f2b(float f) {
  bf16 h = __float2bfloat16(f);
  unsigned short u;
  __builtin_memcpy(&u, &h, 2);
  return u;
}
static __device__ __forceinline__ int iclamp(int v, int lo, int hi) {
  return v < lo ? lo : (v > hi ? hi : v);
}

__global__ __launch_bounds__(256) void zero_out_kernel(float* __restrict__ out) {
  const size_t i = ((size_t)blockIdx.x * 256 + threadIdx.x) * 4;
  floatx4 z = {0.f, 0.f, 0.f, 0.f};
  *reinterpret_cast<floatx4*>(out + i) = z;
}

__global__ void zero_cnt_kernel(int* __restrict__ cnt) {
  if (threadIdx.x < NE) cnt[threadIdx.x] = 0;
}

// f32 -> bf16 (RNE), 8 elements/thread. n must be divisible by grid*256*8.
__global__ __launch_bounds__(256) void cvt_kernel(const float* __restrict__ src,
                                                  bf16* __restrict__ dst) {
  const size_t i = ((size_t)blockIdx.x * 256 + threadIdx.x) * 8;
  const floatx4 a = *reinterpret_cast<const floatx4*>(src + i);
  const floatx4 b = *reinterpret_cast<const floatx4*>(src + i + 4);
  short8 r;
  r[0] = (short)f2b(a[0]); r[1] = (short)f2b(a[1]);
  r[2] = (short)f2b(a[2]); r[3] = (short)f2b(a[3]);
  r[4] = (short)f2b(b[0]); r[5] = (short)f2b(b[1]);
  r[6] = (short)f2b(b[2]); r[7] = (short)f2b(b[3]);
  *reinterpret_cast<short8*>(dst + i) = r;
}

// Router v2 (round-1 fix: was 197 us, latency-bound at 2.7% VALUBusy).
// 256 threads = 4 waves = 4 tokens/block. rw (32 KB) staged in LDS ONCE per
// block (kills the per-wave 128 L2 re-reads of router weights); x row loaded
// up-front as 4 independent float4s. Emits x_bf16 (free: x is read anyway).
__global__ __launch_bounds__(256) void router_kernel(
    const float* __restrict__ x, const float* __restrict__ rw,
    float* __restrict__ rw_out, int* __restrict__ cnt, int* __restrict__ tok,
    float* __restrict__ wslot, bf16* __restrict__ xb) {
  __shared__ float rws[NE * NC];  // 32 KB
  const int tid = threadIdx.x;
  {
    const floatx4* rw4 = reinterpret_cast<const floatx4*>(rw);
    floatx4* rwl4 = reinterpret_cast<floatx4*>(rws);
#pragma unroll
    for (int i = 0; i < 8; ++i) rwl4[i * 256 + tid] = rw4[i * 256 + tid];
  }
  __syncthreads();

  const int wave = tid >> 6;
  const int lane = tid & 63;
  const int t = blockIdx.x * 4 + wave;
  const floatx4* xr4 = reinterpret_cast<const floatx4*>(x + (size_t)t * NC);
  const floatx4* rwl4 = reinterpret_cast<const floatx4*>(rws);
  bf16* xbr = xb + (size_t)t * NC;

  // x row: 4 independent float4 loads in flight together.
  floatx4 xv[4];
#pragma unroll
  for (int i = 0; i < 4; ++i) xv[i] = xr4[i * 64 + lane];

  // bf16 conversion + store (coalesced 8B/lane stores).
#pragma unroll
  for (int i = 0; i < 4; ++i) {
    const int idx = i * 64 + lane;
    short4v o;
    o[0] = (short)f2b(xv[i][0]); o[1] = (short)f2b(xv[i][1]);
    o[2] = (short)f2b(xv[i][2]); o[3] = (short)f2b(xv[i][3]);
    *reinterpret_cast<short4v*>(xbr + idx * 4) = o;
  }

  float acc[NE];
#pragma unroll
  for (int e = 0; e < NE; ++e) acc[e] = 0.f;
#pragma unroll
  for (int i = 0; i < 4; ++i) {
    const int idx = i * 64 + lane;
#pragma unroll
    for (int e = 0; e < NE; ++e) {
      const floatx4 wv = rwl4[e * 256 + idx];
      acc[e] = fmaf(xv[i][0], wv[0], acc[e]);
      acc[e] = fmaf(xv[i][1], wv[1], acc[e]);
      acc[e] = fmaf(xv[i][2], wv[2], acc[e]);
      acc[e] = fmaf(xv[i][3], wv[3], acc[e]);
    }
  }
#pragma unroll
  for (int e = 0; e < NE; ++e) {
#pragma unroll
    for (int off = 32; off; off >>= 1) acc[e] += __shfl_xor(acc[e], off, 64);
  }

  // softmax over 8 (fp32)
  float m = acc[0];
#pragma unroll
  for (int e = 1; e < NE; ++e) m = fmaxf(m, acc[e]);
  float p[NE];
  float s = 0.f;
#pragma unroll
  for (int e = 0; e < NE; ++e) {
    p[e] = __expf(acc[e] - m);
    s += p[e];
  }
  const float inv = 1.f / s;
#pragma unroll
  for (int e = 0; e < NE; ++e) p[e] *= inv;

  if (lane < NE) rw_out[(size_t)t * NE + lane] = p[lane];

  if (lane == 0) {
    // top-2, ties -> lower index first (matches jax top_k)
    int i0 = 0;
    float v0 = p[0];
    int i1 = -1;
    float v1 = -1.f;
#pragma unroll
    for (int e = 1; e < NE; ++e) {
      if (p[e] > v0) {
        v1 = v0; i1 = i0;
        v0 = p[e]; i0 = e;
      } else if (p[e] > v1) {
        v1 = p[e]; i1 = e;
      }
    }
    i0 = iclamp(i0, 0, NE - 1);  // insurance (see round-5 post-mortem)
    i1 = iclamp(i1, 0, NE - 1);
    const float denom = v0 + v1 + 1e-10f;
    const float w0 = v0 / denom, w1 = v1 / denom;

    const int p0 = atomicAdd(&cnt[i0], 1);
    if (p0 < CAP) {
      tok[i0 * CAP + p0] = t;
      wslot[i0 * CAP + p0] = w0;
    }
    const int p1 = atomicAdd(&cnt[i1], 1);
    if (p1 < CAP) {
      tok[i1 * CAP + p1] = t;
      wslot[i1 * CAP + p1] = w1;
    }
  }
}

// Grouped GEMM over one M-chunk per expert. All-bf16 inputs. MFMA 16x16x32,
// 128x128 tile, BK=64, 4 waves (2x2 of 64x64), global_load_lds width-16
// staging (m97), XOR chunk swizzle applied on the GLOBAL source side.
// FC=1: A = x_bf16 gathered via tok, relu^2 epilogue -> hidden chunk (bf16).
// FC=0: A = hidden chunk (bf16), epilogue f32 atomicAdd of w*val into out.
template <bool FC>
__global__ __launch_bounds__(256) void gemm_moe(
    const bf16* __restrict__ Axb, const bf16* __restrict__ Ah,
    const bf16* __restrict__ Bw, bf16* __restrict__ Oh,
    float* __restrict__ Oo, const int* __restrict__ cnt,
    const int* __restrict__ tok, const float* __restrict__ wslot,
    int rowOffset, int mch) {
  constexpr int Kd = FC ? NC : NH;
  constexpr int Nd = FC ? NH : NC;
  const int e = blockIdx.z;
  const int Me = iclamp(cnt[e], 0, CAP);
  const int rowBase = rowOffset + blockIdx.y * 128;  // expert-local row
  if (rowBase >= Me) return;
  const int colBase = blockIdx.x * 128;

  const bf16* __restrict__ Be = Bw + (size_t)e * Nd * Kd;
  const bf16* __restrict__ Ahc = Ah + (size_t)e * mch * NH;

  __shared__ bf16 As[128 * 64];
  __shared__ bf16 Bs[128 * 64];

  const int tid = threadIdx.x;
  const int lane = tid & 63;
  const int wid = tid >> 6;
  const int wm = wid & 1;
  const int wn = wid >> 1;
  const int ml = lane & 15;
  const int quad = lane >> 4;

  // Staging: slot sidx holds (row r = sidx>>3, phys chunk pc = sidx&7);
  // data placed there is logical chunk lc = pc ^ (r&7).
  const bf16* ga[4];
  const bf16* gb[4];
  bf16* la[4];
  bf16* lb[4];
#pragma unroll
  for (int it = 0; it < 4; ++it) {
    const int sidx = it * 256 + tid;
    const int r = sidx >> 3;
    const int pc = sidx & 7;
    const int lc = pc ^ (r & 7);
    if (FC) {
      const int grow = rowBase + r;
      const int tk = (grow < Me) ? tok[e * CAP + grow] : 0;
      const int arow = iclamp(tk, 0, NTOK - 1);  // global token row in x_bf16
      ga[it] = Axb + (size_t)arow * NC + lc * 8;
    } else {
      int grow = rowBase + r;
      if (grow > Me - 1) grow = Me - 1;  // stay inside this expert's rows
      const int arow = iclamp(grow - rowOffset, 0, mch - 1);  // chunk-local
      ga[it] = Ahc + (size_t)arow * NH + lc * 8;
    }
    gb[it] = Be + (size_t)(colBase + r) * Kd + lc * 8;
    la[it] = As + sidx * 8;
    lb[it] = Bs + sidx * 8;
  }

  floatx4 acc[4][4];
#pragma unroll
  for (int mt = 0; mt < 4; ++mt)
#pragma unroll
    for (int nt = 0; nt < 4; ++nt) acc[mt][nt] = floatx4{0.f, 0.f, 0.f, 0.f};

  // Fragment LDS element offsets (per lane): row = ..+ml, chunk q = kk*4+quad
  int aoff[4][2], boff[4][2];
#pragma unroll
  for (int t4 = 0; t4 < 4; ++t4)
#pragma unroll
    for (int kk = 0; kk < 2; ++kk) {
      const int ra = wm * 64 + t4 * 16 + ml;
      const int rb = wn * 64 + t4 * 16 + ml;
      const int q = kk * 4 + quad;
      aoff[t4][kk] = (ra * 8 + (q ^ (ra & 7))) * 8;
      boff[t4][kk] = (rb * 8 + (q ^ (rb & 7))) * 8;
    }

  // Prologue: stage tile k0=0
#pragma unroll
  for (int it = 0; it < 4; ++it) async_copy16(ga[it], la[it]);
#pragma unroll
  for (int it = 0; it < 4; ++it) async_copy16(gb[it], lb[it]);

  const int nkb = Kd >> 6;
  for (int kb = 0; kb < nkb; ++kb) {
    __syncthreads();  // drains vmcnt -> LDS tile ready
    short8 af[4][2], bff[4][2];
#pragma unroll
    for (int mt = 0; mt < 4; ++mt)
#pragma unroll
      for (int kk = 0; kk < 2; ++kk)
        af[mt][kk] = *reinterpret_cast<const short8*>(&As[aoff[mt][kk]]);
#pragma unroll
    for (int nt = 0; nt < 4; ++nt)
#pragma unroll
      for (int kk = 0; kk < 2; ++kk)
        bff[nt][kk] = *reinterpret_cast<const short8*>(&Bs[boff[nt][kk]]);
#pragma unroll
    for (int kk = 0; kk < 2; ++kk)
#pragma unroll
      for (int mt = 0; mt < 4; ++mt)
#pragma unroll
        for (int nt = 0; nt < 4; ++nt)
          acc[mt][nt] = __builtin_amdgcn_mfma_f32_16x16x32_bf16(
              af[mt][kk], bff[nt][kk], acc[mt][nt], 0, 0, 0);
    __syncthreads();  // all ds_reads done before restage
    if (kb + 1 < nkb) {
      const int k0 = (kb + 1) << 6;
#pragma unroll
      for (int it = 0; it < 4; ++it) async_copy16(ga[it] + k0, la[it]);
#pragma unroll
      for (int it = 0; it < 4; ++it) async_copy16(gb[it] + k0, lb[it]);
    }
  }

  // Epilogue: C/D layout col=lane&15, row=quad*4+reg (m89/m91 verified).
  if (FC) {
    bf16* __restrict__ O = Oh + (size_t)e * mch * NH;
    const int rlBase = rowBase - rowOffset;  // chunk-local
#pragma unroll
    for (int mt = 0; mt < 4; ++mt) {
      const int rl = wm * 64 + mt * 16 + quad * 4;
#pragma unroll
      for (int nt = 0; nt < 4; ++nt) {
        const int cc = colBase + wn * 64 + nt * 16 + ml;
        const floatx4 v = acc[mt][nt];
#pragma unroll
        for (int rg = 0; rg < 4; ++rg) {
          if (rowBase + rl + rg < Me) {
            float f = fmaxf(v[rg], 0.f);
            f = f * f;  // relu^2
            O[(size_t)(rlBase + rl + rg) * NH + cc] = __float2bfloat16(f);
          }
        }
      }
    }
  } else {
#pragma unroll
    for (int mt = 0; mt < 4; ++mt) {
      const int rl = wm * 64 + mt * 16 + quad * 4;
#pragma unroll
      for (int rg = 0; rg < 4; ++rg) {
        const int re = rowBase + rl + rg;  // expert-local row
        if (re < Me) {
          const int t = iclamp(tok[e * CAP + re], 0, NTOK - 1);
          const float w = wslot[e * CAP + re];
#pragma unroll
          for (int nt = 0; nt < 4; ++nt) {
            const int cc = colBase + wn * 64 + nt * 16 + ml;
            atomicAdd(Oo + (size_t)t * NC + cc, w * acc[mt][nt][rg]);
          }
        }
      }
    }
  }
}

extern "C" void kernel_launch(void* const* d_in, const int* in_sizes, int n_in,
                              void* d_out, int out_size, void* d_ws,
                              size_t ws_size, hipStream_t stream) {
  const float* x = (const float*)d_in[0];      // [8192, 1024] f32
  const float* rw = (const float*)d_in[1];     // [8, 1024] f32
  const float* fcw = (const float*)d_in[2];    // [8, 2048, 1024] f32
  const float* pjw = (const float*)d_in[3];    // [8, 1024, 2048] f32
  float* out = (float*)d_out;                  // [8192,1024] ++ [8192,8] f32
  float* rw_out = out + (size_t)NTOK * NC;

  // Workspace: bookkeeping 262.4 KB + x_bf16 16.8 MB + fcw_bf16 33.6 MB +
  // pjw_bf16 33.6 MB = 84.2 MB fixed, + bf16 hidden chunk (mch ladder).
  char* ws = (char*)d_ws;
  int* cnt = (int*)ws;                            // 256 B
  int* tok = (int*)(ws + 256);                    // 128 KB
  float* wslot = (float*)(ws + 256 + 131072);     // 128 KB
  bf16* xb = (bf16*)(ws + 262400);                // 16.78 MB
  bf16* fcwb = (bf16*)(ws + 262400 + 16777216);   // 33.55 MB
  bf16* pjwb = (bf16*)(ws + 262400 + 16777216 + 33554432);
  const size_t fixed = 262400 + 16777216 + 2 * 33554432;  // 84.15 MB
  bf16* hidden = (bf16*)(ws + fixed);             // NE * mch * NH bf16
  (void)in_sizes; (void)n_in; (void)out_size;

  int mch = 128;
  for (int cand = CAP; cand >= 128; cand >>= 1) {
    const size_t need = fixed + (size_t)NE * cand * NH * 2;
    if (need <= ws_size) { mch = cand; break; }
  }

  zero_out_kernel<<<NTOK * NC / 1024, 256, 0, stream>>>(out);
  zero_cnt_kernel<<<1, 64, 0, stream>>>(cnt);
  cvt_kernel<<<NE * NH * NC / 2048, 256, 0, stream>>>(fcw, fcwb);
  cvt_kernel<<<NE * NC * NH / 2048, 256, 0, stream>>>(pjw, pjwb);
  router_kernel<<<NTOK / 4, 256, 0, stream>>>(x, rw, rw_out, cnt, tok, wslot, xb);

  for (int c = 0; c < CAP / mch; ++c) {
    // fc: N=H=2048, K=C=1024, gather bf16 x, relu^2 -> hidden chunk
    gemm_moe<true><<<dim3(NH / 128, mch / 128, NE), 256, 0, stream>>>(
        xb, hidden, fcwb, hidden, out, cnt, tok, wslot, c * mch, mch);
    // proj: N=C=1024, K=H=2048, combine w*val into out via f32 atomics
    gemm_moe<false><<<dim3(NC / 128, mch / 128, NE), 256, 0, stream>>>(
        xb, hidden, pjwb, hidden, out, cnt, tok, wslot, c * mch, mch);
  }
}

// Round 3
// 475.014 us; speedup vs baseline: 1.3354x; 1.3354x over previous
//
#include <hip/hip_runtime.h>
#include <hip/hip_bf16.h>
#include <stdint.h>

// Problem constants: B=4, T=2048, C=1024, E=8, H=2048, K=2
#define NB 4
#define NTT 2048
#define NC 1024
#define NE 8
#define NH 2048
#define NKK 2
#define NTOK (NB * NTT)            // 8192
#define CAP (2 * NTOK * NKK / NE)  // 4096

typedef __hip_bfloat16 bf16;
typedef __attribute__((ext_vector_type(8))) short short8;
typedef __attribute__((ext_vector_type(4))) short short4v;
typedef __attribute__((ext_vector_type(4))) float floatx4;
typedef __attribute__((ext_vector_type(2))) float floatx2;

typedef const __attribute__((address_space(1))) void* gas_ptr;
typedef __attribute__((address_space(3))) void* las_ptr;

static __device__ __forceinline__ void async_copy16(const void* g, void* l) {
  // 16B/lane; LDS dest = wave-uniform base + lane*16 (m97/m104 semantics).
  __builtin_amdgcn_global_load_lds((gas_ptr)g, (las_ptr)l, 16, 0, 0);
}

static __device__ __forceinline__ unsigned short f2b(float f) {
  bf16 h = __float2bfloat16(f);
  unsigned short u;
  __builtin_memcpy(&u, &h, 2);
  return u;
}
static __device__ __forceinline__ int iclamp(int v, int lo, int hi) {
  return v < lo ? lo : (v > hi ? hi : v);
}

__global__ __launch_bounds__(256) void zero_out_kernel(float* __restrict__ out) {
  const size_t i = ((size_t)blockIdx.x * 256 + threadIdx.x) * 4;
  floatx4 z = {0.f, 0.f, 0.f, 0.f};
  *reinterpret_cast<floatx4*>(out + i) = z;
}

// f32 -> bf16 (RNE), 8 elements/thread. n must be divisible by grid*256*8.
__global__ __launch_bounds__(256) void cvt_kernel(const float* __restrict__ src,
                                                  bf16* __restrict__ dst) {
  const size_t i = ((size_t)blockIdx.x * 256 + threadIdx.x) * 8;
  const floatx4 a = *reinterpret_cast<const floatx4*>(src + i);
  const floatx4 b = *reinterpret_cast<const floatx4*>(src + i + 4);
  short8 r;
  r[0] = (short)f2b(a[0]); r[1] = (short)f2b(a[1]);
  r[2] = (short)f2b(a[2]); r[3] = (short)f2b(a[3]);
  r[4] = (short)f2b(b[0]); r[5] = (short)f2b(b[1]);
  r[6] = (short)f2b(b[2]); r[7] = (short)f2b(b[3]);
  *reinterpret_cast<short8*>(dst + i) = r;
}

// Router v3 (round-2 fix). v1/v2 both pinned at ~196 us with VALUBusy ~2.8%
// regardless of memory restructure -> bottleneck was the 16384 serialized
// cross-XCD fetch-adds on the single cnt[] cacheline (~12 ns each). v3 is
// ATOMIC-FREE: writes packed top-2 (epair) + normalized weights (wpair);
// slot assignment moved to build_kernel (scan). Emits x_bf16 as before.
__global__ __launch_bounds__(256) void router_kernel(
    const float* __restrict__ x, const float* __restrict__ rw,
    float* __restrict__ rw_out, int* __restrict__ epair,
    float* __restrict__ wpair, bf16* __restrict__ xb) {
  __shared__ float rws[NE * NC];  // 32 KB
  const int tid = threadIdx.x;
  {
    const floatx4* rw4 = reinterpret_cast<const floatx4*>(rw);
    floatx4* rwl4 = reinterpret_cast<floatx4*>(rws);
#pragma unroll
    for (int i = 0; i < 8; ++i) rwl4[i * 256 + tid] = rw4[i * 256 + tid];
  }
  __syncthreads();

  const int wave = tid >> 6;
  const int lane = tid & 63;
  const int t = blockIdx.x * 4 + wave;
  const floatx4* xr4 = reinterpret_cast<const floatx4*>(x + (size_t)t * NC);
  const floatx4* rwl4 = reinterpret_cast<const floatx4*>(rws);
  bf16* xbr = xb + (size_t)t * NC;

  // x row: 4 independent float4 loads in flight together.
  floatx4 xv[4];
#pragma unroll
  for (int i = 0; i < 4; ++i) xv[i] = xr4[i * 64 + lane];

  // bf16 conversion + store (coalesced 8B/lane stores).
#pragma unroll
  for (int i = 0; i < 4; ++i) {
    const int idx = i * 64 + lane;
    short4v o;
    o[0] = (short)f2b(xv[i][0]); o[1] = (short)f2b(xv[i][1]);
    o[2] = (short)f2b(xv[i][2]); o[3] = (short)f2b(xv[i][3]);
    *reinterpret_cast<short4v*>(xbr + idx * 4) = o;
  }

  float acc[NE];
#pragma unroll
  for (int e = 0; e < NE; ++e) acc[e] = 0.f;
#pragma unroll
  for (int i = 0; i < 4; ++i) {
    const int idx = i * 64 + lane;
#pragma unroll
    for (int e = 0; e < NE; ++e) {
      const floatx4 wv = rwl4[e * 256 + idx];
      acc[e] = fmaf(xv[i][0], wv[0], acc[e]);
      acc[e] = fmaf(xv[i][1], wv[1], acc[e]);
      acc[e] = fmaf(xv[i][2], wv[2], acc[e]);
      acc[e] = fmaf(xv[i][3], wv[3], acc[e]);
    }
  }
#pragma unroll
  for (int e = 0; e < NE; ++e) {
#pragma unroll
    for (int off = 32; off; off >>= 1) acc[e] += __shfl_xor(acc[e], off, 64);
  }

  // softmax over 8 (fp32)
  float m = acc[0];
#pragma unroll
  for (int e = 1; e < NE; ++e) m = fmaxf(m, acc[e]);
  float p[NE];
  float s = 0.f;
#pragma unroll
  for (int e = 0; e < NE; ++e) {
    p[e] = __expf(acc[e] - m);
    s += p[e];
  }
  const float inv = 1.f / s;
#pragma unroll
  for (int e = 0; e < NE; ++e) p[e] *= inv;

  if (lane < NE) rw_out[(size_t)t * NE + lane] = p[lane];

  if (lane == 0) {
    // top-2, ties -> lower index first (matches jax top_k)
    int i0 = 0;
    float v0 = p[0];
    int i1 = -1;
    float v1 = -1.f;
#pragma unroll
    for (int e = 1; e < NE; ++e) {
      if (p[e] > v0) {
        v1 = v0; i1 = i0;
        v0 = p[e]; i0 = e;
      } else if (p[e] > v1) {
        v1 = p[e]; i1 = e;
      }
    }
    i0 = iclamp(i0, 0, NE - 1);  // insurance
    i1 = iclamp(i1, 0, NE - 1);
    const float denom = v0 + v1 + 1e-10f;
    epair[t] = i0 | (i1 << 16);
    floatx2 wv;
    wv[0] = v0 / denom;
    wv[1] = v1 / denom;
    *reinterpret_cast<floatx2*>(wpair + 2 * t) = wv;
  }
}

// One block per expert. Each thread owns a CONTIGUOUS 32-token chunk ->
// block-wide exclusive scan gives slot bases; within-expert slot order is
// exactly flat-index order (t*2+s), i.e. the reference's stable argsort,
// including capacity-overflow drop order. Zero global atomics.
__global__ __launch_bounds__(256) void build_kernel(
    const int* __restrict__ epair, const float* __restrict__ wpair,
    int* __restrict__ cnt, int* __restrict__ tok, float* __restrict__ wslot) {
  const int e = blockIdx.x;
  const int tid = threadIdx.x;
  const int lane = tid & 63;
  const int wave = tid >> 6;
  constexpr int TPT = NTOK / 256;  // 32 tokens per thread
  const int t0 = tid * TPT;

  int pe[TPT];
#pragma unroll
  for (int i = 0; i < TPT; i += 4) {
    const int4 v = *reinterpret_cast<const int4*>(epair + t0 + i);
    pe[i] = v.x; pe[i + 1] = v.y; pe[i + 2] = v.z; pe[i + 3] = v.w;
  }
  int c = 0;
#pragma unroll
  for (int i = 0; i < TPT; ++i)
    c += (((pe[i] & 0xffff) == e) ? 1 : 0) + (((pe[i] >> 16) == e) ? 1 : 0);

  // exclusive scan of c across 256 threads (wave shfl scan + LDS wave sums)
  int incl = c;
#pragma unroll
  for (int off = 1; off < 64; off <<= 1) {
    const int up = __shfl_up(incl, off, 64);
    if (lane >= off) incl += up;
  }
  __shared__ int wsum[4];
  if (lane == 63) wsum[wave] = incl;
  __syncthreads();
  int base = incl - c;
#pragma unroll
  for (int w = 0; w < 4; ++w)
    if (w < wave) base += wsum[w];
  if (tid == 255) cnt[e] = base + c;  // total (may exceed CAP; gemm clamps)

#pragma unroll
  for (int i = 0; i < TPT; ++i) {
    const int t = t0 + i;
    if ((pe[i] & 0xffff) == e) {
      if (base < CAP) {
        tok[e * CAP + base] = t;
        wslot[e * CAP + base] = wpair[2 * t];
      }
      ++base;
    }
    if ((pe[i] >> 16) == e) {
      if (base < CAP) {
        tok[e * CAP + base] = t;
        wslot[e * CAP + base] = wpair[2 * t + 1];
      }
      ++base;
    }
  }
}

// Grouped GEMM over one M-chunk per expert. All-bf16 inputs. MFMA 16x16x32,
// 128x128 tile, BK=64, 4 waves (2x2 of 64x64), global_load_lds width-16
// staging (m97), XOR chunk swizzle applied on the GLOBAL source side.
// FC=1: A = x_bf16 gathered via tok, relu^2 epilogue -> hidden chunk (bf16).
// FC=0: A = hidden chunk (bf16), epilogue f32 atomicAdd of w*val into out.
template <bool FC>
__global__ __launch_bounds__(256) void gemm_moe(
    const bf16* __restrict__ Axb, const bf16* __restrict__ Ah,
    const bf16* __restrict__ Bw, bf16* __restrict__ Oh,
    float* __restrict__ Oo, const int* __restrict__ cnt,
    const int* __restrict__ tok, const float* __restrict__ wslot,
    int rowOffset, int mch) {
  constexpr int Kd = FC ? NC : NH;
  constexpr int Nd = FC ? NH : NC;
  const int e = blockIdx.z;
  const int Me = iclamp(cnt[e], 0, CAP);
  const int rowBase = rowOffset + blockIdx.y * 128;  // expert-local row
  if (rowBase >= Me) return;
  const int colBase = blockIdx.x * 128;

  const bf16* __restrict__ Be = Bw + (size_t)e * Nd * Kd;
  const bf16* __restrict__ Ahc = Ah + (size_t)e * mch * NH;

  __shared__ bf16 As[128 * 64];
  __shared__ bf16 Bs[128 * 64];

  const int tid = threadIdx.x;
  const int lane = tid & 63;
  const int wid = tid >> 6;
  const int wm = wid & 1;
  const int wn = wid >> 1;
  const int ml = lane & 15;
  const int quad = lane >> 4;

  // Staging: slot sidx holds (row r = sidx>>3, phys chunk pc = sidx&7);
  // data placed there is logical chunk lc = pc ^ (r&7).
  const bf16* ga[4];
  const bf16* gb[4];
  bf16* la[4];
  bf16* lb[4];
#pragma unroll
  for (int it = 0; it < 4; ++it) {
    const int sidx = it * 256 + tid;
    const int r = sidx >> 3;
    const int pc = sidx & 7;
    const int lc = pc ^ (r & 7);
    if (FC) {
      const int grow = rowBase + r;
      const int tk = (grow < Me) ? tok[e * CAP + grow] : 0;
      const int arow = iclamp(tk, 0, NTOK - 1);  // global token row in x_bf16
      ga[it] = Axb + (size_t)arow * NC + lc * 8;
    } else {
      int grow = rowBase + r;
      if (grow > Me - 1) grow = Me - 1;  // stay inside this expert's rows
      const int arow = iclamp(grow - rowOffset, 0, mch - 1);  // chunk-local
      ga[it] = Ahc + (size_t)arow * NH + lc * 8;
    }
    gb[it] = Be + (size_t)(colBase + r) * Kd + lc * 8;
    la[it] = As + sidx * 8;
    lb[it] = Bs + sidx * 8;
  }

  floatx4 acc[4][4];
#pragma unroll
  for (int mt = 0; mt < 4; ++mt)
#pragma unroll
    for (int nt = 0; nt < 4; ++nt) acc[mt][nt] = floatx4{0.f, 0.f, 0.f, 0.f};

  // Fragment LDS element offsets (per lane): row = ..+ml, chunk q = kk*4+quad
  int aoff[4][2], boff[4][2];
#pragma unroll
  for (int t4 = 0; t4 < 4; ++t4)
#pragma unroll
    for (int kk = 0; kk < 2; ++kk) {
      const int ra = wm * 64 + t4 * 16 + ml;
      const int rb = wn * 64 + t4 * 16 + ml;
      const int q = kk * 4 + quad;
      aoff[t4][kk] = (ra * 8 + (q ^ (ra & 7))) * 8;
      boff[t4][kk] = (rb * 8 + (q ^ (rb & 7))) * 8;
    }

  // Prologue: stage tile k0=0
#pragma unroll
  for (int it = 0; it < 4; ++it) async_copy16(ga[it], la[it]);
#pragma unroll
  for (int it = 0; it < 4; ++it) async_copy16(gb[it], lb[it]);

  const int nkb = Kd >> 6;
  for (int kb = 0; kb < nkb; ++kb) {
    __syncthreads();  // drains vmcnt -> LDS tile ready
    short8 af[4][2], bff[4][2];
#pragma unroll
    for (int mt = 0; mt < 4; ++mt)
#pragma unroll
      for (int kk = 0; kk < 2; ++kk)
        af[mt][kk] = *reinterpret_cast<const short8*>(&As[aoff[mt][kk]]);
#pragma unroll
    for (int nt = 0; nt < 4; ++nt)
#pragma unroll
      for (int kk = 0; kk < 2; ++kk)
        bff[nt][kk] = *reinterpret_cast<const short8*>(&Bs[boff[nt][kk]]);
#pragma unroll
    for (int kk = 0; kk < 2; ++kk)
#pragma unroll
      for (int mt = 0; mt < 4; ++mt)
#pragma unroll
        for (int nt = 0; nt < 4; ++nt)
          acc[mt][nt] = __builtin_amdgcn_mfma_f32_16x16x32_bf16(
              af[mt][kk], bff[nt][kk], acc[mt][nt], 0, 0, 0);
    __syncthreads();  // all ds_reads done before restage
    if (kb + 1 < nkb) {
      const int k0 = (kb + 1) << 6;
#pragma unroll
      for (int it = 0; it < 4; ++it) async_copy16(ga[it] + k0, la[it]);
#pragma unroll
      for (int it = 0; it < 4; ++it) async_copy16(gb[it] + k0, lb[it]);
    }
  }

  // Epilogue: C/D layout col=lane&15, row=quad*4+reg (m89/m91 verified).
  if (FC) {
    bf16* __restrict__ O = Oh + (size_t)e * mch * NH;
    const int rlBase = rowBase - rowOffset;  // chunk-local
#pragma unroll
    for (int mt = 0; mt < 4; ++mt) {
      const int rl = wm * 64 + mt * 16 + quad * 4;
#pragma unroll
      for (int nt = 0; nt < 4; ++nt) {
        const int cc = colBase + wn * 64 + nt * 16 + ml;
        const floatx4 v = acc[mt][nt];
#pragma unroll
        for (int rg = 0; rg < 4; ++rg) {
          if (rowBase + rl + rg < Me) {
            float f = fmaxf(v[rg], 0.f);
            f = f * f;  // relu^2
            O[(size_t)(rlBase + rl + rg) * NH + cc] = __float2bfloat16(f);
          }
        }
      }
    }
  } else {
#pragma unroll
    for (int mt = 0; mt < 4; ++mt) {
      const int rl = wm * 64 + mt * 16 + quad * 4;
#pragma unroll
      for (int rg = 0; rg < 4; ++rg) {
        const int re = rowBase + rl + rg;  // expert-local row
        if (re < Me) {
          const int t = iclamp(tok[e * CAP + re], 0, NTOK - 1);
          const float w = wslot[e * CAP + re];
#pragma unroll
          for (int nt = 0; nt < 4; ++nt) {
            const int cc = colBase + wn * 64 + nt * 16 + ml;
            atomicAdd(Oo + (size_t)t * NC + cc, w * acc[mt][nt][rg]);
          }
        }
      }
    }
  }
}

extern "C" void kernel_launch(void* const* d_in, const int* in_sizes, int n_in,
                              void* d_out, int out_size, void* d_ws,
                              size_t ws_size, hipStream_t stream) {
  const float* x = (const float*)d_in[0];      // [8192, 1024] f32
  const float* rw = (const float*)d_in[1];     // [8, 1024] f32
  const float* fcw = (const float*)d_in[2];    // [8, 2048, 1024] f32
  const float* pjw = (const float*)d_in[3];    // [8, 1024, 2048] f32
  float* out = (float*)d_out;                  // [8192,1024] ++ [8192,8] f32
  float* rw_out = out + (size_t)NTOK * NC;

  // Workspace layout:
  // cnt 256B | tok 128KB | wslot 128KB | epair 32KB | wpair 64KB |
  // xb 16.78MB | fcwb 33.55MB | pjwb 33.55MB | hidden (mch ladder)
  char* ws = (char*)d_ws;
  int* cnt = (int*)ws;                              // 256 B
  int* tok = (int*)(ws + 256);                      // 128 KB
  float* wslot = (float*)(ws + 256 + 131072);       // 128 KB
  int* epair = (int*)(ws + 262400);                 // 32 KB
  float* wpair = (float*)(ws + 262400 + 32768);     // 64 KB
  bf16* xb = (bf16*)(ws + 360704);                  // 16.78 MB
  bf16* fcwb = (bf16*)(ws + 360704 + 16777216);     // 33.55 MB
  bf16* pjwb = (bf16*)(ws + 360704 + 16777216 + 33554432);
  const size_t fixed = 360704 + 16777216 + 2 * 33554432;  // 84.25 MB
  bf16* hidden = (bf16*)(ws + fixed);               // NE * mch * NH bf16
  (void)in_sizes; (void)n_in; (void)out_size;

  int mch = 128;
  for (int cand = CAP; cand >= 128; cand >>= 1) {
    const size_t need = fixed + (size_t)NE * cand * NH * 2;
    if (need <= ws_size) { mch = cand; break; }
  }

  zero_out_kernel<<<NTOK * NC / 1024, 256, 0, stream>>>(out);
  cvt_kernel<<<NE * NH * NC / 2048, 256, 0, stream>>>(fcw, fcwb);
  cvt_kernel<<<NE * NC * NH / 2048, 256, 0, stream>>>(pjw, pjwb);
  router_kernel<<<NTOK / 4, 256, 0, stream>>>(x, rw, rw_out, epair, wpair, xb);
  build_kernel<<<NE, 256, 0, stream>>>(epair, wpair, cnt, tok, wslot);

  for (int c = 0; c < CAP / mch; ++c) {
    // fc: N=H=2048, K=C=1024, gather bf16 x, relu^2 -> hidden chunk
    gemm_moe<true><<<dim3(NH / 128, mch / 128, NE), 256, 0, stream>>>(
        xb, hidden, fcwb, hidden, out, cnt, tok, wslot, c * mch, mch);
    // proj: N=C=1024, K=H=2048, combine w*val into out via f32 atomics
    gemm_moe<false><<<dim3(NC / 128, mch / 128, NE), 256, 0, stream>>>(
        xb, hidden, pjwb, hidden, out, cnt, tok, wslot, c * mch, mch);
  }
}